// Round 10
// baseline (224.062 us; speedup 1.0000x reference)
//
#include <hip/hip_runtime.h>
#include <hip/hip_bf16.h>

typedef short short8 __attribute__((ext_vector_type(8)));
typedef short short4v __attribute__((ext_vector_type(4)));
typedef float f32x4 __attribute__((ext_vector_type(4)));

#define E 256
#define DH 128

__device__ __forceinline__ float bf2f(__hip_bfloat16 x) { return __bfloat162float(x); }
__device__ __forceinline__ __hip_bfloat16 f2bf(float x) { return __float2bfloat16(x); }

__device__ __forceinline__ short8 cvt8(float4 a, float4 b) {
    __hip_bfloat16 t[8] = {f2bf(a.x), f2bf(a.y), f2bf(a.z), f2bf(a.w),
                           f2bf(b.x), f2bf(b.y), f2bf(b.z), f2bf(b.w)};
    return *reinterpret_cast<const short8*>(t);
}
__device__ __forceinline__ short8 ld_cvt8(const float* p) {
    return cvt8(*reinterpret_cast<const float4*>(p),
                *reinterpret_cast<const float4*>(p + 4));
}

// ---------- projection GEMM: out[M,256] = A[M,256] @ W^T + b; A,W fp32, inline cvt ----------
struct ProjSeg { const float* A; const float* W; const float* b; __hip_bfloat16* out; };
struct ProjArgs { ProjSeg seg[5]; };

__global__ __launch_bounds__(256) void gemm_proj(ProjArgs args, int M)
{
    int wv = threadIdx.x >> 6, lane = threadIdx.x & 63;
    int m0 = blockIdx.x * 32;
    if (m0 >= M) return;
    ProjSeg sg = args.seg[blockIdx.y];
    int lo = lane & 15, hi = lane >> 4;

    const float* ar0  = sg.A + (size_t)(m0 + lo) * E + hi * 8;
    const float* ar1  = ar0 + 16 * E;
    const float* brow = sg.W + (size_t)(wv * 64 + lo) * E + hi * 8;

    f32x4 acc[2][4] = {};
#pragma unroll
    for (int k = 0; k < 8; ++k) {
        short8 a0 = ld_cvt8(ar0 + k * 32);
        short8 a1 = ld_cvt8(ar1 + k * 32);
#pragma unroll
        for (int nt = 0; nt < 4; ++nt) {
            short8 b = ld_cvt8(brow + (size_t)nt * 16 * E + k * 32);
            acc[0][nt] = __builtin_amdgcn_mfma_f32_16x16x32_bf16(a0, b, acc[0][nt], 0, 0, 0);
            acc[1][nt] = __builtin_amdgcn_mfma_f32_16x16x32_bf16(a1, b, acc[1][nt], 0, 0, 0);
        }
    }
#pragma unroll
    for (int nt = 0; nt < 4; ++nt) {
        int col = wv * 64 + nt * 16 + lo;
        float bias = sg.b[col];
#pragma unroll
        for (int mt = 0; mt < 2; ++mt)
#pragma unroll
            for (int r = 0; r < 4; ++r) {
                int row = m0 + mt * 16 + hi * 4 + r;
                sg.out[(size_t)row * E + col] = f2bf(acc[mt][nt][r] + bias);
            }
    }
}

// ---------- fused: sparse attn (16 faces, 1/wave) -> outproj -> LN [-> Q1 epilogue] ----------
// r6-verified structure: 1024 threads = 16 waves; wave w does face m0+w attention,
// outproj col-stripe [w*16,w*16+16) via sm tile, LN of row w by wave-butterfly.
// Optional epilogue (wq1 != null): restage y into atile (bf16), MFMA vs wq1 -> q1out.
__global__ __launch_bounds__(1024) void attn_outproj_ln(
    const int* __restrict__ rel, const __hip_bfloat16* __restrict__ q16,
    const __hip_bfloat16* __restrict__ k16, const __hip_bfloat16* __restrict__ v16,
    const float* __restrict__ wout, const float* __restrict__ bout,
    const float* __restrict__ resid, const float* __restrict__ lng, const float* __restrict__ lnb,
    float* __restrict__ outp,
    const float* __restrict__ wq1, const float* __restrict__ bq1,
    __hip_bfloat16* __restrict__ q1out, int L, int ML)
{
    __shared__ __align__(16) __hip_bfloat16 atile[16 * 264];  // stride 264: 2-way banks (free)
    __shared__ __align__(16) float sm[16 * 260];
    __shared__ __align__(16) float lds_w[16][2][16];          // [face][head][edge]
    __shared__ int lds_idx[16][16];

    int tid = threadIdx.x, wv = tid >> 6, lane = tid & 63;
    int m0 = blockIdx.x * 16;
    int g = lane >> 2, q = lane & 3;
    int face = m0 + wv;
    const float scale = 0.088388347648318447f;  // 1/sqrt(128)

    // ---- attention: one face per wave ----
    const int* rr = rel + (size_t)face * ML;
    int myidx = (g < ML) ? rr[g] : -1;

    bool dup = false;
#pragma unroll
    for (int d = 1; d < 16; ++d) {
        int other = __shfl(myidx, ((g - d) & 15) * 4 + q);
        if (d <= g && other == myidx) dup = true;
    }
    bool myuse = (myidx >= 0) && !dup;       // set semantics: unique valid edges
    int safe = myidx < 0 ? 0 : myidx;
    if (q == 0) lds_idx[wv][g] = safe;

#pragma unroll
    for (int h = 0; h < 2; ++h) {
        const __hip_bfloat16* kbase = k16 + (size_t)safe * E + h * DH;
        const __hip_bfloat16* qbase = q16 + (size_t)face * E + h * DH;
        float part = 0.f;
#pragma unroll
        for (int t = 0; t < 4; ++t) {
            short8 qv = *reinterpret_cast<const short8*>(qbase + (t * 4 + q) * 8);
            short8 kv = *reinterpret_cast<const short8*>(kbase + (t * 4 + q) * 8);
            const __hip_bfloat16* qp = (const __hip_bfloat16*)&qv;
            const __hip_bfloat16* kp = (const __hip_bfloat16*)&kv;
#pragma unroll
            for (int e2 = 0; e2 < 8; ++e2)
                part += bf2f(qp[e2]) * bf2f(kp[e2]);
        }
        part += __shfl_xor(part, 1);
        part += __shfl_xor(part, 2);          // full 128-dim dot in all 4 quad lanes
        float sc = myuse ? part * scale : -1e30f;
        float mx = sc;
#pragma unroll
        for (int off = 4; off < 64; off <<= 1) mx = fmaxf(mx, __shfl_xor(mx, off));
        float e = __expf(sc - mx);            // exactly 0 for dead slots
        float den = e;
#pragma unroll
        for (int off = 4; off < 64; off <<= 1) den += __shfl_xor(den, off);
        if (q == 0) lds_w[wv][h][g] = e / den;
    }

    // V phase: lane covers dims [4*lane, 4*lane+4) of the 256-dim row
    {
        int h = lane >> 5;
        float a0 = 0.f, a1 = 0.f, a2 = 0.f, a3 = 0.f;
#pragma unroll
        for (int j = 0; j < 16; ++j) {
            int ij = lds_idx[wv][j];
            float wj = lds_w[wv][h][j];       // 0 for unused edges
            short4v vv = *reinterpret_cast<const short4v*>(v16 + (size_t)ij * E + 4 * lane);
            const __hip_bfloat16* vp = (const __hip_bfloat16*)&vv;
            a0 += wj * bf2f(vp[0]);
            a1 += wj * bf2f(vp[1]);
            a2 += wj * bf2f(vp[2]);
            a3 += wj * bf2f(vp[3]);
        }
        __hip_bfloat16 ob[4] = {f2bf(a0), f2bf(a1), f2bf(a2), f2bf(a3)};
        *reinterpret_cast<short4v*>(atile + wv * 264 + 4 * lane) =
            *reinterpret_cast<const short4v*>(ob);
    }
    __syncthreads();

    // ---- outproj MFMA: wave wv -> cols [wv*16, wv*16+16), via sm tile ----
    int lo = lane & 15, hi = lane >> 4;
    {
        const __hip_bfloat16* arow = atile + lo * 264 + hi * 8;
        const float* browf = wout + (size_t)(wv * 16 + lo) * E + hi * 8;
        f32x4 acc = {0.f, 0.f, 0.f, 0.f};
#pragma unroll
        for (int kk = 0; kk < 8; ++kk) {
            short8 a = *reinterpret_cast<const short8*>(arow + kk * 32);
            short8 b = ld_cvt8(browf + kk * 32);
            acc = __builtin_amdgcn_mfma_f32_16x16x32_bf16(a, b, acc, 0, 0, 0);
        }
        int col = wv * 16 + lo;
#pragma unroll
        for (int r = 0; r < 4; ++r)
            sm[(hi * 4 + r) * 260 + col] = acc[r];
    }
    __syncthreads();

    // ---- LN: wave wv handles row wv; lane covers 4 cols ----
    {
        int rowg = m0 + wv;
        float4 pv = *reinterpret_cast<const float4*>(sm + wv * 260 + 4 * lane);
        float4 rv = *reinterpret_cast<const float4*>(resid + (size_t)rowg * E + 4 * lane);
        float4 bb = *reinterpret_cast<const float4*>(bout + 4 * lane);
        float v0 = pv.x + bb.x + rv.x;
        float v1 = pv.y + bb.y + rv.y;
        float v2 = pv.z + bb.z + rv.z;
        float v3 = pv.w + bb.w + rv.w;
        float s  = v0 + v1 + v2 + v3;
        float s2 = v0 * v0 + v1 * v1 + v2 * v2 + v3 * v3;
#pragma unroll
        for (int off = 1; off < 64; off <<= 1) {
            s  += __shfl_xor(s, off);
            s2 += __shfl_xor(s2, off);
        }
        float mean = s * (1.f / 256.f);
        float var  = s2 * (1.f / 256.f) - mean * mean;
        float rstd = rsqrtf(var + 1e-5f);
        float4 gg = *reinterpret_cast<const float4*>(lng + 4 * lane);
        float4 b2 = *reinterpret_cast<const float4*>(lnb + 4 * lane);
        float y0 = (v0 - mean) * rstd * gg.x + b2.x;
        float y1 = (v1 - mean) * rstd * gg.y + b2.y;
        float y2 = (v2 - mean) * rstd * gg.z + b2.z;
        float y3 = (v3 - mean) * rstd * gg.w + b2.w;
        float4 o = {y0, y1, y2, y3};
        *reinterpret_cast<float4*>(outp + (size_t)rowg * E + 4 * lane) = o;
        if (wq1) {  // restage y (bf16) for the fused Q1 projection
            __hip_bfloat16 ob[4] = {f2bf(y0), f2bf(y1), f2bf(y2), f2bf(y3)};
            *reinterpret_cast<short4v*>(atile + wv * 264 + 4 * lane) =
                *reinterpret_cast<const short4v*>(ob);
        }
    }

    // ---- optional Q1 epilogue: q1out = y @ wq1^T + bq1 ----
    if (wq1) {
        __syncthreads();
        const __hip_bfloat16* arow = atile + lo * 264 + hi * 8;
        const float* browf = wq1 + (size_t)(wv * 16 + lo) * E + hi * 8;
        f32x4 acc = {0.f, 0.f, 0.f, 0.f};
#pragma unroll
        for (int kk = 0; kk < 8; ++kk) {
            short8 a = *reinterpret_cast<const short8*>(arow + kk * 32);
            short8 b = ld_cvt8(browf + kk * 32);
            acc = __builtin_amdgcn_mfma_f32_16x16x32_bf16(a, b, acc, 0, 0, 0);
        }
        int col = wv * 16 + lo;
        float bias = bq1[col];
#pragma unroll
        for (int r = 0; r < 4; ++r)
            q1out[(size_t)(m0 + hi * 4 + r) * E + col] = f2bf(acc[r] + bias);
    }
}

extern "C" void kernel_launch(void* const* d_in, const int* in_sizes, int n_in,
                              void* d_out, int out_size, void* d_ws, size_t ws_size,
                              hipStream_t stream) {
    const int* rel = (const int*)d_in[0];
    const float* edge = (const float*)d_in[2];
    const float* face = (const float*)d_in[3];
    const float* w_in[2]  = {(const float*)d_in[4],  (const float*)d_in[10]};
    const float* b_in[2]  = {(const float*)d_in[5],  (const float*)d_in[11]};
    const float* w_out[2] = {(const float*)d_in[6],  (const float*)d_in[12]};
    const float* b_out[2] = {(const float*)d_in[7],  (const float*)d_in[13]};
    const float* ln_g[2]  = {(const float*)d_in[8],  (const float*)d_in[14]};
    const float* ln_b[2]  = {(const float*)d_in[9],  (const float*)d_in[15]};

    int S = in_sizes[2] / E;
    int L = in_sizes[3] / E;
    int ML = in_sizes[0] / L;

    char* ws = (char*)d_ws;
    __hip_bfloat16* q16 = (__hip_bfloat16*)ws;    ws += (size_t)L * E * 2;
    __hip_bfloat16* k16[2], *v16[2];
    for (int l = 0; l < 2; ++l) {
        k16[l] = (__hip_bfloat16*)ws; ws += (size_t)S * E * 2;
        v16[l] = (__hip_bfloat16*)ws; ws += (size_t)S * E * 2;
    }
    float* xres = (float*)ws;                     ws += (size_t)L * E * 4;

    float* outp = (float*)d_out;

    // 1) Q0 + K0,V0,K1,V1 projections — one launch, 5 segments, fp32 A and W
    {
        ProjArgs pa;
        pa.seg[0] = {face, w_in[0],                     b_in[0],         q16};
        pa.seg[1] = {edge, w_in[0] + (size_t)E * E,     b_in[0] + E,     k16[0]};
        pa.seg[2] = {edge, w_in[0] + (size_t)2 * E * E, b_in[0] + 2 * E, v16[0]};
        pa.seg[3] = {edge, w_in[1] + (size_t)E * E,     b_in[1] + E,     k16[1]};
        pa.seg[4] = {edge, w_in[1] + (size_t)2 * E * E, b_in[1] + 2 * E, v16[1]};
        gemm_proj<<<dim3(L / 32, 5), 256, 0, stream>>>(pa, L);
    }

    // 2) layer 0: attn + outproj + LN -> xres; fused Q1 projection -> q16
    attn_outproj_ln<<<L / 16, 1024, 0, stream>>>(rel, q16, k16[0], v16[0],
                                                 w_out[0], b_out[0], face,
                                                 ln_g[0], ln_b[0], xres,
                                                 w_in[1], b_in[1], q16, L, ML);

    // 3) layer 1: attn + outproj + LN -> d_out
    attn_outproj_ln<<<L / 16, 1024, 0, stream>>>(rel, q16, k16[1], v16[1],
                                                 w_out[1], b_out[1], xres,
                                                 ln_g[1], ln_b[1], outp,
                                                 nullptr, nullptr, nullptr, L, ML);
}

// Round 11
// 185.206 us; speedup vs baseline: 1.2098x; 1.2098x over previous
//
#include <hip/hip_runtime.h>
#include <hip/hip_bf16.h>

typedef short short8 __attribute__((ext_vector_type(8)));
typedef short short4v __attribute__((ext_vector_type(4)));
typedef float f32x4 __attribute__((ext_vector_type(4)));

#define E 256
#define DH 128

__device__ __forceinline__ float bf2f(__hip_bfloat16 x) { return __bfloat162float(x); }
__device__ __forceinline__ __hip_bfloat16 f2bf(float x) { return __float2bfloat16(x); }

__device__ __forceinline__ short8 cvt8(float4 a, float4 b) {
    __hip_bfloat16 t[8] = {f2bf(a.x), f2bf(a.y), f2bf(a.z), f2bf(a.w),
                           f2bf(b.x), f2bf(b.y), f2bf(b.z), f2bf(b.w)};
    return *reinterpret_cast<const short8*>(t);
}

// ---------- fused fp32 -> bf16 convert (edge + 4 weight arrays) ----------
struct CvtArgs { const float* in[5]; __hip_bfloat16* out[5]; int n[5]; };

__global__ __launch_bounds__(256) void f2b_all(CvtArgs a)
{
    int seg = blockIdx.y;
    int i = (blockIdx.x * 256 + threadIdx.x) * 8;
    if (i >= a.n[seg]) return;
    const float* in = a.in[seg];
    float4 x = *reinterpret_cast<const float4*>(in + i);
    float4 y = *reinterpret_cast<const float4*>(in + i + 4);
    *reinterpret_cast<short8*>(a.out[seg] + i) = cvt8(x, y);
}

// ---------- K/V projection GEMM: out[S,256] = edge16 @ W^T + b (all bf16) ----------
struct ProjSeg { const __hip_bfloat16* W; const float* b; __hip_bfloat16* out; };
struct ProjArgs { const __hip_bfloat16* A; ProjSeg seg[4]; };

__global__ __launch_bounds__(256) void gemm_proj(ProjArgs args, int M)
{
    int wv = threadIdx.x >> 6, lane = threadIdx.x & 63;
    int m0 = blockIdx.x * 32;
    if (m0 >= M) return;
    ProjSeg sg = args.seg[blockIdx.y];
    int lo = lane & 15, hi = lane >> 4;

    const __hip_bfloat16* ar0 = args.A + (size_t)(m0 + lo) * E + hi * 8;
    const __hip_bfloat16* ar1 = ar0 + 16 * E;
    const __hip_bfloat16* brow = sg.W + (size_t)(wv * 64 + lo) * E + hi * 8;

    f32x4 acc[2][4] = {};
#pragma unroll
    for (int k = 0; k < 8; ++k) {
        short8 a0 = *reinterpret_cast<const short8*>(ar0 + k * 32);
        short8 a1 = *reinterpret_cast<const short8*>(ar1 + k * 32);
#pragma unroll
        for (int nt = 0; nt < 4; ++nt) {
            short8 b = *reinterpret_cast<const short8*>(brow + (size_t)nt * 16 * E + k * 32);
            acc[0][nt] = __builtin_amdgcn_mfma_f32_16x16x32_bf16(a0, b, acc[0][nt], 0, 0, 0);
            acc[1][nt] = __builtin_amdgcn_mfma_f32_16x16x32_bf16(a1, b, acc[1][nt], 0, 0, 0);
        }
    }
#pragma unroll
    for (int nt = 0; nt < 4; ++nt) {
        int col = wv * 64 + nt * 16 + lo;
        float bias = sg.b[col];
#pragma unroll
        for (int mt = 0; mt < 2; ++mt)
#pragma unroll
            for (int r = 0; r < 4; ++r) {
                int row = m0 + mt * 16 + hi * 4 + r;
                sg.out[(size_t)row * E + col] = f2bf(acc[mt][nt][r] + bias);
            }
    }
}

// ---------- mega-fused: Q0 -> attn0 -> outproj0+LN0 -> Q1 -> attn1 -> outproj1+LN1 ----------
// 16 faces/block, 1024 threads = 16 waves. Wave w: face m0+w for attention phases,
// 16-col stripe [w*16,w*16+16) for all GEMM phases, row w for LN phases.
// y0 (LN0 output, fp32) stays in registers as LN1's residual. K/V per layer are
// precomputed from edge (they don't depend on x), which makes the whole pipeline row-local.
__global__ __launch_bounds__(1024) void mega_fused(
    const int* __restrict__ rel, const float* __restrict__ facef,
    const __hip_bfloat16* __restrict__ wq0, const float* __restrict__ bq0,
    const __hip_bfloat16* __restrict__ k0, const __hip_bfloat16* __restrict__ v0,
    const __hip_bfloat16* __restrict__ wout0, const float* __restrict__ bout0,
    const float* __restrict__ ln0g, const float* __restrict__ ln0b,
    const __hip_bfloat16* __restrict__ wq1, const float* __restrict__ bq1,
    const __hip_bfloat16* __restrict__ k1, const __hip_bfloat16* __restrict__ v1,
    const __hip_bfloat16* __restrict__ wout1, const float* __restrict__ bout1,
    const float* __restrict__ ln1g, const float* __restrict__ ln1b,
    float* __restrict__ outp, int L, int ML)
{
    __shared__ __align__(16) __hip_bfloat16 ftile[16 * 264];  // x rows bf16 (face, later y0)
    __shared__ __align__(16) __hip_bfloat16 qtile[16 * 264];  // Q rows bf16
    __shared__ __align__(16) __hip_bfloat16 atile[16 * 264];  // attn out bf16
    __shared__ __align__(16) float sm[16 * 260];              // outproj fp32
    __shared__ __align__(16) float lds_w[16][2][16];          // [face][head][edge]
    __shared__ int lds_idx[16][16];

    int tid = threadIdx.x, wv = tid >> 6, lane = tid & 63;
    int m0 = blockIdx.x * 16;
    int g = lane >> 2, q = lane & 3;
    int face = m0 + wv;
    int lo = lane & 15, hi = lane >> 4;
    const float scale = 0.088388347648318447f;  // 1/sqrt(128)

    // ---- dedupe ONCE (mask identical for both layers) ----
    const int* rr = rel + (size_t)face * ML;
    int myidx = (g < ML) ? rr[g] : -1;
    bool dup = false;
#pragma unroll
    for (int d = 1; d < 16; ++d) {
        int other = __shfl(myidx, ((g - d) & 15) * 4 + q);
        if (d <= g && other == myidx) dup = true;
    }
    bool myuse = (myidx >= 0) && !dup;       // set semantics: unique valid edges
    int safe = myidx < 0 ? 0 : myidx;
    if (q == 0) lds_idx[wv][g] = safe;

    // ---- stage face row bf16 into ftile ----
    {
        float4 fv = *reinterpret_cast<const float4*>(facef + (size_t)face * E + 4 * lane);
        __hip_bfloat16 fb[4] = {f2bf(fv.x), f2bf(fv.y), f2bf(fv.z), f2bf(fv.w)};
        *reinterpret_cast<short4v*>(ftile + wv * 264 + 4 * lane) =
            *reinterpret_cast<const short4v*>(fb);
    }
    __syncthreads();

    float yk[4];  // LN output row wv, cols 4*lane..4*lane+3 (residual carry)

#pragma unroll
    for (int layer = 0; layer < 2; ++layer) {
        const __hip_bfloat16* wq    = layer ? wq1 : wq0;
        const float*          bq    = layer ? bq1 : bq0;
        const __hip_bfloat16* kk16  = layer ? k1 : k0;
        const __hip_bfloat16* vv16  = layer ? v1 : v0;
        const __hip_bfloat16* wo    = layer ? wout1 : wout0;
        const float*          bo    = layer ? bout1 : bout0;
        const float*          lg    = layer ? ln1g : ln0g;
        const float*          lb    = layer ? ln1b : ln0b;

        // ---- Q projection: wave wv -> cols [wv*16, wv*16+16) for all 16 faces ----
        {
            const __hip_bfloat16* arow = ftile + lo * 264 + hi * 8;
            const __hip_bfloat16* brow = wq + (size_t)(wv * 16 + lo) * E + hi * 8;
            f32x4 acc = {0.f, 0.f, 0.f, 0.f};
#pragma unroll
            for (int kki = 0; kki < 8; ++kki) {
                short8 a = *reinterpret_cast<const short8*>(arow + kki * 32);
                short8 b = *reinterpret_cast<const short8*>(brow + kki * 32);
                acc = __builtin_amdgcn_mfma_f32_16x16x32_bf16(a, b, acc, 0, 0, 0);
            }
            int col = wv * 16 + lo;
            float bias = bq[col];
#pragma unroll
            for (int r = 0; r < 4; ++r)
                qtile[(hi * 4 + r) * 264 + col] = f2bf(acc[r] + bias);
        }
        __syncthreads();

        // ---- attention: one face per wave; Q from qtile (LDS) ----
#pragma unroll
        for (int h = 0; h < 2; ++h) {
            const __hip_bfloat16* kbase = kk16 + (size_t)safe * E + h * DH;
            const __hip_bfloat16* qbase = qtile + wv * 264 + h * DH;
            float part = 0.f;
#pragma unroll
            for (int t = 0; t < 4; ++t) {
                short8 qv = *reinterpret_cast<const short8*>(qbase + (t * 4 + q) * 8);
                short8 kv = *reinterpret_cast<const short8*>(kbase + (t * 4 + q) * 8);
                const __hip_bfloat16* qp = (const __hip_bfloat16*)&qv;
                const __hip_bfloat16* kp = (const __hip_bfloat16*)&kv;
#pragma unroll
                for (int e2 = 0; e2 < 8; ++e2)
                    part += bf2f(qp[e2]) * bf2f(kp[e2]);
            }
            part += __shfl_xor(part, 1);
            part += __shfl_xor(part, 2);      // full 128-dim dot in all 4 quad lanes
            float sc = myuse ? part * scale : -1e30f;
            float mx = sc;
#pragma unroll
            for (int off = 4; off < 64; off <<= 1) mx = fmaxf(mx, __shfl_xor(mx, off));
            float e = __expf(sc - mx);        // exactly 0 for dead slots
            float den = e;
#pragma unroll
            for (int off = 4; off < 64; off <<= 1) den += __shfl_xor(den, off);
            if (q == 0) lds_w[wv][h][g] = e / den;
        }
        // V phase: lane covers dims [4*lane, 4*lane+4)
        {
            int h = lane >> 5;
            float a0 = 0.f, a1 = 0.f, a2 = 0.f, a3 = 0.f;
#pragma unroll
            for (int j = 0; j < 16; ++j) {
                int ij = lds_idx[wv][j];
                float wj = lds_w[wv][h][j];   // 0 for unused edges
                short4v vv = *reinterpret_cast<const short4v*>(vv16 + (size_t)ij * E + 4 * lane);
                const __hip_bfloat16* vp = (const __hip_bfloat16*)&vv;
                a0 += wj * bf2f(vp[0]);
                a1 += wj * bf2f(vp[1]);
                a2 += wj * bf2f(vp[2]);
                a3 += wj * bf2f(vp[3]);
            }
            __hip_bfloat16 ob[4] = {f2bf(a0), f2bf(a1), f2bf(a2), f2bf(a3)};
            *reinterpret_cast<short4v*>(atile + wv * 264 + 4 * lane) =
                *reinterpret_cast<const short4v*>(ob);
        }
        __syncthreads();

        // ---- outproj MFMA: wave wv -> cols [wv*16, wv*16+16), into sm ----
        {
            const __hip_bfloat16* arow = atile + lo * 264 + hi * 8;
            const __hip_bfloat16* brow = wo + (size_t)(wv * 16 + lo) * E + hi * 8;
            f32x4 acc = {0.f, 0.f, 0.f, 0.f};
#pragma unroll
            for (int kki = 0; kki < 8; ++kki) {
                short8 a = *reinterpret_cast<const short8*>(arow + kki * 32);
                short8 b = *reinterpret_cast<const short8*>(brow + kki * 32);
                acc = __builtin_amdgcn_mfma_f32_16x16x32_bf16(a, b, acc, 0, 0, 0);
            }
            int col = wv * 16 + lo;
#pragma unroll
            for (int r = 0; r < 4; ++r)
                sm[(hi * 4 + r) * 260 + col] = acc[r];
        }
        __syncthreads();

        // ---- LN: wave wv -> row wv; residual = face (layer0) or yk regs (layer1) ----
        {
            float4 pv = *reinterpret_cast<const float4*>(sm + wv * 260 + 4 * lane);
            float4 bb = *reinterpret_cast<const float4*>(bo + 4 * lane);
            float r0, r1, r2, r3;
            if (layer == 0) {
                float4 rv = *reinterpret_cast<const float4*>(facef + (size_t)face * E + 4 * lane);
                r0 = rv.x; r1 = rv.y; r2 = rv.z; r3 = rv.w;
            } else {
                r0 = yk[0]; r1 = yk[1]; r2 = yk[2]; r3 = yk[3];
            }
            float v0 = pv.x + bb.x + r0;
            float v1 = pv.y + bb.y + r1;
            float v2 = pv.z + bb.z + r2;
            float v3 = pv.w + bb.w + r3;
            float s  = v0 + v1 + v2 + v3;
            float s2 = v0 * v0 + v1 * v1 + v2 * v2 + v3 * v3;
#pragma unroll
            for (int off = 1; off < 64; off <<= 1) {
                s  += __shfl_xor(s, off);
                s2 += __shfl_xor(s2, off);
            }
            float mean = s * (1.f / 256.f);
            float var  = s2 * (1.f / 256.f) - mean * mean;
            float rstd = rsqrtf(var + 1e-5f);
            float4 gg = *reinterpret_cast<const float4*>(lg + 4 * lane);
            float4 b2 = *reinterpret_cast<const float4*>(lb + 4 * lane);
            float y0 = (v0 - mean) * rstd * gg.x + b2.x;
            float y1 = (v1 - mean) * rstd * gg.y + b2.y;
            float y2 = (v2 - mean) * rstd * gg.z + b2.z;
            float y3 = (v3 - mean) * rstd * gg.w + b2.w;
            if (layer == 0) {
                yk[0] = y0; yk[1] = y1; yk[2] = y2; yk[3] = y3;
                __hip_bfloat16 yb[4] = {f2bf(y0), f2bf(y1), f2bf(y2), f2bf(y3)};
                *reinterpret_cast<short4v*>(ftile + wv * 264 + 4 * lane) =
                    *reinterpret_cast<const short4v*>(yb);
            } else {
                float4 o = {y0, y1, y2, y3};
                *reinterpret_cast<float4*>(outp + (size_t)face * E + 4 * lane) = o;
            }
        }
        if (layer == 0) __syncthreads();   // ftile(y0) ready for layer-1 Q projection
    }
}

extern "C" void kernel_launch(void* const* d_in, const int* in_sizes, int n_in,
                              void* d_out, int out_size, void* d_ws, size_t ws_size,
                              hipStream_t stream) {
    const int* rel = (const int*)d_in[0];
    const float* edge = (const float*)d_in[2];
    const float* face = (const float*)d_in[3];
    const float* w_in[2]  = {(const float*)d_in[4],  (const float*)d_in[10]};
    const float* b_in[2]  = {(const float*)d_in[5],  (const float*)d_in[11]};
    const float* w_out[2] = {(const float*)d_in[6],  (const float*)d_in[12]};
    const float* b_out[2] = {(const float*)d_in[7],  (const float*)d_in[13]};
    const float* ln_g[2]  = {(const float*)d_in[8],  (const float*)d_in[14]};
    const float* ln_b[2]  = {(const float*)d_in[9],  (const float*)d_in[15]};

    int S = in_sizes[2] / E;
    int L = in_sizes[3] / E;
    int ML = in_sizes[0] / L;

    char* ws = (char*)d_ws;
    __hip_bfloat16* edge16 = (__hip_bfloat16*)ws; ws += (size_t)S * E * 2;
    __hip_bfloat16* k16[2], *v16[2];
    for (int l = 0; l < 2; ++l) {
        k16[l] = (__hip_bfloat16*)ws; ws += (size_t)S * E * 2;
        v16[l] = (__hip_bfloat16*)ws; ws += (size_t)S * E * 2;
    }
    __hip_bfloat16* win16[2], *wout16[2];
    for (int l = 0; l < 2; ++l) {
        win16[l]  = (__hip_bfloat16*)ws; ws += (size_t)3 * E * E * 2;
        wout16[l] = (__hip_bfloat16*)ws; ws += (size_t)E * E * 2;
    }

    float* outp = (float*)d_out;

    // 1) conversions: edge + weights (one launch)
    {
        CvtArgs ca;
        ca.in[0] = edge;     ca.out[0] = edge16;    ca.n[0] = S * E;
        ca.in[1] = w_in[0];  ca.out[1] = win16[0];  ca.n[1] = 3 * E * E;
        ca.in[2] = w_in[1];  ca.out[2] = win16[1];  ca.n[2] = 3 * E * E;
        ca.in[3] = w_out[0]; ca.out[3] = wout16[0]; ca.n[3] = E * E;
        ca.in[4] = w_out[1]; ca.out[4] = wout16[1]; ca.n[4] = E * E;
        int gx = (S * E) / (256 * 8);
        f2b_all<<<dim3(gx, 5), 256, 0, stream>>>(ca);
    }

    // 2) K0,V0,K1,V1 projections (edge-derived; x-independent) — one launch, 4 segments
    {
        ProjArgs pa;
        pa.A = edge16;
        pa.seg[0] = {win16[0] + (size_t)E * E,     b_in[0] + E,     k16[0]};
        pa.seg[1] = {win16[0] + (size_t)2 * E * E, b_in[0] + 2 * E, v16[0]};
        pa.seg[2] = {win16[1] + (size_t)E * E,     b_in[1] + E,     k16[1]};
        pa.seg[3] = {win16[1] + (size_t)2 * E * E, b_in[1] + 2 * E, v16[1]};
        gemm_proj<<<dim3(S / 32, 4), 256, 0, stream>>>(pa, S);
    }

    // 3) mega-fused both layers -> d_out
    mega_fused<<<L / 16, 1024, 0, stream>>>(rel, face,
                                            win16[0], b_in[0], k16[0], v16[0],
                                            wout16[0], b_out[0], ln_g[0], ln_b[0],
                                            win16[1], b_in[1], k16[1], v16[1],
                                            wout16[1], b_out[1], ln_g[1], ln_b[1],
                                            outp, L, ML);
}